// Round 5
// baseline (305.226 us; speedup 1.0000x reference)
//
#include <hip/hip_runtime.h>
#include <math.h>

// GNO2d spectral conv, factored into pruned DFT stages (fp32 throughout).
// B=8, Ci=Co=32, T=128, X=256, P=3; modes: kt in {0..15}u{112..127}, kx 0..15, kz 0..1.
typedef float2 F2;

__device__ __forceinline__ F2 cmul(F2 a, F2 b) {
    return make_float2(a.x * b.x - a.y * b.y, a.x * b.y + a.y * b.x);
}
__device__ __forceinline__ F2 cmac(F2 acc, F2 a, F2 b) {
    acc.x += a.x * b.x - a.y * b.y;
    acc.y += a.x * b.y + a.y * b.x;
    return acc;
}

#define TWO_PI 6.283185307179586f
#define SQRT3_2 0.8660254037844386f
#define SQRT3 1.7320508075688772f

// TW16[k] = e^{-2pi i k/16} as constexpr tables -> constant-folded after unroll.
__device__ constexpr float TW16X[16] = {
    1.f,  0.923879533f,  0.707106781f,  0.382683432f,  0.f, -0.382683432f,
    -0.707106781f, -0.923879533f, -1.f, -0.923879533f, -0.707106781f,
    -0.382683432f, 0.f,  0.382683432f,  0.707106781f,  0.923879533f};
__device__ constexpr float TW16Y[16] = {
    0.f, -0.382683432f, -0.707106781f, -0.923879533f, -1.f, -0.923879533f,
    -0.707106781f, -0.382683432f, 0.f,  0.382683432f,  0.707106781f,
    0.923879533f,  1.f,  0.923879533f,  0.707106781f,  0.382683432f};

// ---------------------------------------------------------------------------
// K1 v5: x [row=(b,i,t)][256][3] -> y [row][kz(2)][kx(16)] complex
// Factored twiddle: tw[kx*x] = tw[4uc]*TW16[(ub)&15]*tbase[b]*c0(a)*(-1)^(au).
// LDS stride 260 (== 4 mod 32): hot-loop reads conflict-free.
// ---------------------------------------------------------------------------
__global__ __launch_bounds__(256) void k1_fwd_x(const float* __restrict__ x,
                                                F2* __restrict__ y) {
    __shared__ float xp0[8][260];
    __shared__ F2    xp1[8][260];
    __shared__ F2    tw[256];       // tw[n] = e^{-2pi i n/256}
    __shared__ F2    part[1024];    // [rr][kz][kx][c]
    const int tid = threadIdx.x;
    const int blk = blockIdx.x;     // 8 rows per block, 4096 blocks

    {   // twiddle table
        float sv, cv;
        sincosf(-TWO_PI * (float)tid * (1.0f / 256.0f), &sv, &cv);
        tw[tid] = make_float2(cv, sv);
    }
    // p-stage into LDS
#pragma unroll
    for (int j = 0; j < 8; ++j) {
        int item = tid + 256 * j;           // 2048 = 8 rows * 256 x
        int row = item >> 8, xx = item & 255;
        const float* src = x + ((size_t)(blk * 8 + row) * 256 + xx) * 3;
        float a = src[0], b = src[1], c = src[2];
        xp0[row][xx] = a + b + c;
        xp1[row][xx] = make_float2(a - 0.5f * (b + c), SQRT3_2 * (c - b));
    }
    __syncthreads();

    const int kz = tid >> 7, rr = (tid >> 4) & 7, kxg = (tid >> 2) & 3, c = tid & 3;
    const float sgn = (kxg & 1) ? -1.0f : 1.0f;

    // c0(a) = tw[(32 a kxg) & 255], a = 1..3
    const F2 c01 = tw[(32 * kxg) & 255];
    const F2 c02 = tw[(64 * kxg) & 255];
    const F2 c03 = tw[(96 * kxg) & 255];
    // tw4c[u] = tw[(4 u c) & 255], u = 1..3
    const F2 f1 = tw[(4 * c) & 255];
    const F2 f2 = tw[(8 * c) & 255];
    const F2 f3 = tw[(12 * c) & 255];

    F2 T0[8], T1[8];
    if (kz == 0) {
        const float* r0 = xp0[rr];
#pragma unroll
        for (int b = 0; b < 8; ++b) {
            int x0 = c + 4 * b;
            float s0 = fmaf(sgn, r0[x0 + 128], r0[x0]);
            float s1 = fmaf(sgn, r0[x0 + 160], r0[x0 + 32]);
            float s2 = fmaf(sgn, r0[x0 + 192], r0[x0 + 64]);
            float s3 = fmaf(sgn, r0[x0 + 224], r0[x0 + 96]);
            F2 p1 = make_float2(s1 * c01.x, s1 * c01.y);
            F2 p2 = make_float2(s2 * c02.x, s2 * c02.y);
            F2 p3 = make_float2(s3 * c03.x, s3 * c03.y);
            T0[b] = make_float2(s0 + p1.x + p2.x + p3.x, p1.y + p2.y + p3.y);
            T1[b] = make_float2(s0 - p1.x + p2.x - p3.x, -p1.y + p2.y - p3.y);
        }
    } else {
        const F2* r1 = xp1[rr];
#pragma unroll
        for (int b = 0; b < 8; ++b) {
            int x0 = c + 4 * b;
            F2 a0 = r1[x0],      b0 = r1[x0 + 128];
            F2 a1 = r1[x0 + 32], b1 = r1[x0 + 160];
            F2 a2 = r1[x0 + 64], b2 = r1[x0 + 192];
            F2 a3 = r1[x0 + 96], b3 = r1[x0 + 224];
            F2 s0 = make_float2(fmaf(sgn, b0.x, a0.x), fmaf(sgn, b0.y, a0.y));
            F2 s1 = make_float2(fmaf(sgn, b1.x, a1.x), fmaf(sgn, b1.y, a1.y));
            F2 s2 = make_float2(fmaf(sgn, b2.x, a2.x), fmaf(sgn, b2.y, a2.y));
            F2 s3 = make_float2(fmaf(sgn, b3.x, a3.x), fmaf(sgn, b3.y, a3.y));
            F2 p1 = cmul(s1, c01);
            F2 p2 = cmul(s2, c02);
            F2 p3 = cmul(s3, c03);
            T0[b] = make_float2(s0.x + p1.x + p2.x + p3.x, s0.y + p1.y + p2.y + p3.y);
            T1[b] = make_float2(s0.x - p1.x + p2.x - p3.x, s0.y - p1.y + p2.y - p3.y);
        }
    }

    // ACC: acc[u] = tw4c[u] * sum_b TW16[(u*b)&15] * (tbase[b] * T_{u&1}[b])
    F2 acc0 = make_float2(0.f, 0.f), acc1 = acc0, acc2 = acc0, acc3 = acc0;
#pragma unroll
    for (int b = 0; b < 8; ++b) {
        F2 tb = tw[(kxg * (c + 4 * b)) & 255];
        F2 q0 = cmul(tb, T0[b]);
        F2 q1 = cmul(tb, T1[b]);
        acc0.x += q0.x; acc0.y += q0.y;
        {
            const float Cx = TW16X[(2 * b) & 15], Cy = TW16Y[(2 * b) & 15];
            acc2.x += q0.x * Cx - q0.y * Cy;
            acc2.y += q0.x * Cy + q0.y * Cx;
        }
        {
            const float Cx = TW16X[b & 15], Cy = TW16Y[b & 15];
            acc1.x += q1.x * Cx - q1.y * Cy;
            acc1.y += q1.x * Cy + q1.y * Cx;
        }
        {
            const float Cx = TW16X[(3 * b) & 15], Cy = TW16Y[(3 * b) & 15];
            acc3.x += q1.x * Cx - q1.y * Cy;
            acc3.y += q1.x * Cy + q1.y * Cx;
        }
    }
    acc1 = cmul(acc1, f1);
    acc2 = cmul(acc2, f2);
    acc3 = cmul(acc3, f3);

    {
        const int base = (((rr * 2 + kz) * 16 + kxg) << 2) + c;  // kx = kxg + 4u
        part[base]       = acc0;
        part[base + 16]  = acc1;
        part[base + 32]  = acc2;
        part[base + 48]  = acc3;
    }
    __syncthreads();
    {
        int rr2 = tid >> 5, kz2 = (tid >> 4) & 1, kx2 = tid & 15;
        const F2* p = &part[((rr2 * 2 + kz2) * 16 + kx2) << 2];
        F2 r = p[0];
        r.x += p[1].x + p[2].x + p[3].x;
        r.y += p[1].y + p[2].y + p[3].y;
        y[((size_t)(blk * 8 + rr2) * 2 + kz2) * 16 + kx2] = r;
    }
}

// ---------------------------------------------------------------------------
// K2a: y [(b,i),t,kz,kx] -> x_ft [b][s(32)][kz][kx][i] complex
// x_ft[s] = sum_t y[t] e^{-2pi i kt(s) t/128}, kt = s (s<16) else 96+s
// ---------------------------------------------------------------------------
__global__ __launch_bounds__(256) void k2a_fwd_t(const F2* __restrict__ y,
                                                 F2* __restrict__ xft) {
    __shared__ F2 yL[128][16];
    const int tid = threadIdx.x;
    const int bi = blockIdx.x >> 1, kz = blockIdx.x & 1;   // 512 blocks
#pragma unroll
    for (int j = 0; j < 8; ++j) {
        int item = tid + 256 * j;       // 2048 = 128 t * 16 kx
        int t = item >> 4, kx = item & 15;
        yL[t][kx] = y[((size_t)(bi * 128 + t) * 2 + kz) * 16 + kx];
    }
    __syncthreads();

    const int kx = tid & 15, sg = tid >> 4;   // sg in [0,16)
    F2 rotA = make_float2(1.f, 0.f), rotB = make_float2(1.f, 0.f), stepA, stepB;
    sincosf(-TWO_PI * (float)sg * (1.0f / 128.0f), &stepA.y, &stepA.x);
    sincosf(-TWO_PI * (float)(112 + sg) * (1.0f / 128.0f), &stepB.y, &stepB.x);
    F2 accA = make_float2(0.f, 0.f), accB = make_float2(0.f, 0.f);
#pragma unroll 8
    for (int t = 0; t < 128; ++t) {
        F2 v = yL[t][kx];
        accA = cmac(accA, v, rotA);
        accB = cmac(accB, v, rotB);
        rotA = cmul(rotA, stepA);
        rotB = cmul(rotB, stepB);
    }
    const int b = bi >> 5, i = bi & 31;
    xft[(((size_t)(b * 32 + sg) * 2 + kz) * 16 + kx) * 32 + i] = accA;
    xft[(((size_t)(b * 32 + (16 + sg)) * 2 + kz) * 16 + kx) * 32 + i] = accB;
}

// ---------------------------------------------------------------------------
// K2b: mode mix. block per (s,kx) (512 blocks); thread = (b,o).
// ---------------------------------------------------------------------------
__global__ __launch_bounds__(256) void k2b_mix(const F2* __restrict__ xft,
                                               const float* __restrict__ w1re,
                                               const float* __restrict__ w1im,
                                               const float* __restrict__ w2re,
                                               const float* __restrict__ w2im,
                                               F2* __restrict__ blkout) {
    __shared__ F2 xL[512];            // [b][kz][i]
    __shared__ F2 wcL[2][32][32];     // [kz][i][o] (re, im)
    const int tid = threadIdx.x;
    const int s = blockIdx.x >> 4, kx = blockIdx.x & 15;
#pragma unroll
    for (int j = 0; j < 2; ++j) {
        int item = tid + 256 * j;     // 512 = 8b * 2kz * 32i
        int b = item >> 6, kz = (item >> 5) & 1, i = item & 31;
        xL[item] = xft[(((size_t)(b * 32 + s) * 2 + kz) * 16 + kx) * 32 + i];
    }
    const float* bre = (s < 16) ? w1re : w2re;
    const float* bim = (s < 16) ? w1im : w2im;
    const int m1 = s & 15;
#pragma unroll
    for (int j = 0; j < 4; ++j) {
        int iop = tid + 256 * j;      // 1024 = 32i * 32o
        int i = iop >> 5, o = iop & 31;
        size_t g = (((size_t)(i * 32 + o) * 16 + m1) * 16 + kx) * 3;  // m3=0,1 adjacent
        wcL[0][i][o] = make_float2(bre[g], bim[g]);
        wcL[1][i][o] = make_float2(bre[g + 1], bim[g + 1]);
    }
    __syncthreads();

    const int b = tid >> 5, o = tid & 31;
#pragma unroll
    for (int kz = 0; kz < 2; ++kz) {
        F2 acc = make_float2(0.f, 0.f);
#pragma unroll 8
        for (int i = 0; i < 32; ++i) {
            F2 xv = xL[(b * 2 + kz) * 32 + i];   // broadcast across o
            F2 wv = wcL[kz][i][o];
            acc.x += xv.x * wv.x - xv.y * wv.y;
            acc.y += xv.x * wv.y + xv.y * wv.x;
        }
        blkout[(((size_t)(b * 32 + o) * 32 + s) * 2 + kz) * 16 + kx] = acc;
    }
}

// ---------------------------------------------------------------------------
// K23 v2: fused inverse-t + inverse-x + irfft(P=3).
// block = (bo, tc) (1024 blocks). Phase 1 = K2c body -> hT[32][32] in LDS.
// Phase 2 = K3 body reading hT, staged in oL, coalesced float4 write-back.
// v2 fixes vs v1 (83 us, 244 VGPR, 10% occupancy):
//  - #pragma unroll 1 on the x-column loop: ONE rotator chain live, not 4.
//  - __launch_bounds__(256, 4): cap at 128 VGPR -> 4 waves/SIMD.
//  - bL/oL share LDS (bL dead after phase 1): 40 KB -> 32 KB.
// ---------------------------------------------------------------------------
__global__ __launch_bounds__(256, 4) void k23_inv_tx(const F2* __restrict__ blkin,
                                                     float* __restrict__ out) {
    // pool: phase 1 = bL[1024] F2 (8 KB); phase 2 = oL[8][768] float (24 KB)
    __shared__ __align__(16) unsigned char pool[24576];
    __shared__ F2 hT[32][32];                            // [t_local][col]
    F2* bL = (F2*)pool;
    float (*oL)[768] = (float (*)[768])pool;
    const int tid = threadIdx.x;
    const int bo = blockIdx.x >> 2, tc = blockIdx.x & 3; // 1024 blocks

#pragma unroll
    for (int j = 0; j < 4; ++j) {
        int item = tid + 256 * j;
        bL[item] = blkin[(size_t)bo * 1024 + item];
    }
    __syncthreads();

    // ---- phase 1: inverse t (verbatim K2c compute) ----
    {
        const int col = tid & 31, tl = tid >> 5;  // t = 32*tc + tl + 8*q
        F2 accA[4], accB[4], w[4], stp[4];
#pragma unroll
        for (int q = 0; q < 4; ++q) {
            accA[q] = make_float2(0.f, 0.f);
            accB[q] = make_float2(0.f, 0.f);
            w[q] = make_float2(1.f, 0.f);
            int t = 32 * tc + tl + 8 * q;
            sincosf(TWO_PI * (float)t * (1.0f / 128.0f), &stp[q].y, &stp[q].x);
        }
#pragma unroll 4
        for (int sp = 0; sp < 16; ++sp) {
            F2 bA = bL[sp * 32 + col];
            F2 bB = bL[(16 + sp) * 32 + col];
#pragma unroll
            for (int q = 0; q < 4; ++q) {
                accA[q] = cmac(accA[q], bA, w[q]);
                accB[q] = cmac(accB[q], bB, w[q]);
                w[q] = cmul(w[q], stp[q]);
            }
        }
        F2 phase;
        sincosf(-TWO_PI * (float)tl * (1.0f / 8.0f), &phase.y, &phase.x);
#pragma unroll
        for (int q = 0; q < 4; ++q) {
            hT[tl + 8 * q][col] = cmac(accA[q], phase, accB[q]);
        }
    }
    __syncthreads();   // hT ready; bL dead -> pool becomes oL

    // ---- phase 2: inverse x + irfft(P=3), 4 rounds of 8 t-rows ----
    const int xg = tid & 31, tl2 = tid >> 5;  // tl2 in [0,8)
    const float n = 1.0f / 98304.0f;          // 1/(128*256*3)
    for (int rd = 0; rd < 4; ++rd) {
        const F2* hrow = &hT[rd * 8 + tl2][0];
        float* o = oL[tl2];
#pragma unroll 1
        for (int j = 0; j < 4; ++j) {
            const int x = xg + 32 * j;        // x in [0,128)
            F2 w = make_float2(1.f, 0.f), r;
            sincosf(TWO_PI * (float)x * (1.0f / 256.0f), &r.y, &r.x);
            float e0 = 0.f, o0 = 0.f;
            F2 e1 = make_float2(0.f, 0.f), o1 = make_float2(0.f, 0.f);
#pragma unroll
            for (int k2 = 0; k2 < 8; ++k2) {
                {   // even kx = 2*k2
                    F2 h0 = hrow[2 * k2], h1 = hrow[16 + 2 * k2];
                    e0 += h0.x * w.x - h0.y * w.y;
                    e1.x += h1.x * w.x - h1.y * w.y;
                    e1.y += h1.x * w.y + h1.y * w.x;
                    w = cmul(w, r);
                }
                {   // odd kx = 2*k2+1
                    F2 h0 = hrow[2 * k2 + 1], h1 = hrow[16 + 2 * k2 + 1];
                    o0 += h0.x * w.x - h0.y * w.y;
                    o1.x += h1.x * w.x - h1.y * w.y;
                    o1.y += h1.x * w.y + h1.y * w.x;
                    w = cmul(w, r);
                }
            }
            {
                float g0 = e0 + o0, g1r = e1.x + o1.x, g1i = e1.y + o1.y;
                o[x * 3 + 0] = n * (g0 + 2.f * g1r);
                o[x * 3 + 1] = n * (g0 - g1r - SQRT3 * g1i);
                o[x * 3 + 2] = n * (g0 - g1r + SQRT3 * g1i);
            }
            {
                float g0 = e0 - o0, g1r = e1.x - o1.x, g1i = e1.y - o1.y;
                int xb = x + 128;
                o[xb * 3 + 0] = n * (g0 + 2.f * g1r);
                o[xb * 3 + 1] = n * (g0 - g1r - SQRT3 * g1i);
                o[xb * 3 + 2] = n * (g0 - g1r + SQRT3 * g1i);
            }
        }
        __syncthreads();
        {   // coalesced write-back of 8 rows: 1536 float4
            float4* dst = (float4*)(out + ((size_t)bo * 128 + 32 * tc + 8 * rd) * 768);
            const float4* src = (const float4*)pool;
#pragma unroll
            for (int k = 0; k < 6; ++k) dst[tid + 256 * k] = src[tid + 256 * k];
        }
        __syncthreads();   // before oL is overwritten next round
    }
}

// ---------------------------------------------------------------------------
extern "C" void kernel_launch(void* const* d_in, const int* in_sizes, int n_in,
                              void* d_out, int out_size, void* d_ws, size_t ws_size,
                              hipStream_t stream) {
    const float* x    = (const float*)d_in[0];
    const float* w1re = (const float*)d_in[1];
    const float* w1im = (const float*)d_in[2];
    const float* w2re = (const float*)d_in[3];
    const float* w2im = (const float*)d_in[4];
    float* out = (float*)d_out;

    // workspace layout (float2 units): y 1048576 | xft 262144 | blk 262144
    F2* y   = (F2*)d_ws;
    F2* xft = y + 1048576;
    F2* bk  = xft + 262144;

    hipLaunchKernelGGL(k1_fwd_x,   dim3(4096), dim3(256), 0, stream, x, y);
    hipLaunchKernelGGL(k2a_fwd_t,  dim3(512),  dim3(256), 0, stream, y, xft);
    hipLaunchKernelGGL(k2b_mix,    dim3(512),  dim3(256), 0, stream, xft,
                       w1re, w1im, w2re, w2im, bk);
    hipLaunchKernelGGL(k23_inv_tx, dim3(1024), dim3(256), 0, stream, bk, out);
}

// Round 6
// 256.347 us; speedup vs baseline: 1.1907x; 1.1907x over previous
//
#include <hip/hip_runtime.h>
#include <math.h>

// GNO2d spectral conv, factored into pruned DFT stages (fp32 throughout).
// B=8, Ci=Co=32, T=128, X=256, P=3; modes: kt in {0..15}u{112..127}, kx 0..15, kz 0..1.
typedef float2 F2;

__device__ __forceinline__ F2 cmul(F2 a, F2 b) {
    return make_float2(a.x * b.x - a.y * b.y, a.x * b.y + a.y * b.x);
}
__device__ __forceinline__ F2 cmac(F2 acc, F2 a, F2 b) {
    acc.x += a.x * b.x - a.y * b.y;
    acc.y += a.x * b.y + a.y * b.x;
    return acc;
}

#define TWO_PI 6.283185307179586f
#define SQRT3_2 0.8660254037844386f
#define SQRT3 1.7320508075688772f

// TW16[k] = e^{-2pi i k/16} as constexpr tables -> constant-folded after unroll.
__device__ constexpr float TW16X[16] = {
    1.f,  0.923879533f,  0.707106781f,  0.382683432f,  0.f, -0.382683432f,
    -0.707106781f, -0.923879533f, -1.f, -0.923879533f, -0.707106781f,
    -0.382683432f, 0.f,  0.382683432f,  0.707106781f,  0.923879533f};
__device__ constexpr float TW16Y[16] = {
    0.f, -0.382683432f, -0.707106781f, -0.923879533f, -1.f, -0.923879533f,
    -0.707106781f, -0.382683432f, 0.f,  0.382683432f,  0.707106781f,
    0.923879533f,  1.f,  0.923879533f,  0.707106781f,  0.382683432f};

// ---------------------------------------------------------------------------
// K1 v5: x [row=(b,i,t)][256][3] -> y [row][kz(2)][kx(16)] complex
// Factored twiddle: tw[kx*x] = tw[4uc]*TW16[(ub)&15]*tbase[b]*c0(a)*(-1)^(au).
// LDS stride 260 (== 4 mod 32): hot-loop reads conflict-free.
// ---------------------------------------------------------------------------
__global__ __launch_bounds__(256) void k1_fwd_x(const float* __restrict__ x,
                                                F2* __restrict__ y) {
    __shared__ float xp0[8][260];
    __shared__ F2    xp1[8][260];
    __shared__ F2    tw[256];       // tw[n] = e^{-2pi i n/256}
    __shared__ F2    part[1024];    // [rr][kz][kx][c]
    const int tid = threadIdx.x;
    const int blk = blockIdx.x;     // 8 rows per block, 4096 blocks

    {   // twiddle table
        float sv, cv;
        sincosf(-TWO_PI * (float)tid * (1.0f / 256.0f), &sv, &cv);
        tw[tid] = make_float2(cv, sv);
    }
    // p-stage into LDS
#pragma unroll
    for (int j = 0; j < 8; ++j) {
        int item = tid + 256 * j;           // 2048 = 8 rows * 256 x
        int row = item >> 8, xx = item & 255;
        const float* src = x + ((size_t)(blk * 8 + row) * 256 + xx) * 3;
        float a = src[0], b = src[1], c = src[2];
        xp0[row][xx] = a + b + c;
        xp1[row][xx] = make_float2(a - 0.5f * (b + c), SQRT3_2 * (c - b));
    }
    __syncthreads();

    const int kz = tid >> 7, rr = (tid >> 4) & 7, kxg = (tid >> 2) & 3, c = tid & 3;
    const float sgn = (kxg & 1) ? -1.0f : 1.0f;

    // c0(a) = tw[(32 a kxg) & 255], a = 1..3
    const F2 c01 = tw[(32 * kxg) & 255];
    const F2 c02 = tw[(64 * kxg) & 255];
    const F2 c03 = tw[(96 * kxg) & 255];
    // tw4c[u] = tw[(4 u c) & 255], u = 1..3
    const F2 f1 = tw[(4 * c) & 255];
    const F2 f2 = tw[(8 * c) & 255];
    const F2 f3 = tw[(12 * c) & 255];

    F2 T0[8], T1[8];
    if (kz == 0) {
        const float* r0 = xp0[rr];
#pragma unroll
        for (int b = 0; b < 8; ++b) {
            int x0 = c + 4 * b;
            float s0 = fmaf(sgn, r0[x0 + 128], r0[x0]);
            float s1 = fmaf(sgn, r0[x0 + 160], r0[x0 + 32]);
            float s2 = fmaf(sgn, r0[x0 + 192], r0[x0 + 64]);
            float s3 = fmaf(sgn, r0[x0 + 224], r0[x0 + 96]);
            F2 p1 = make_float2(s1 * c01.x, s1 * c01.y);
            F2 p2 = make_float2(s2 * c02.x, s2 * c02.y);
            F2 p3 = make_float2(s3 * c03.x, s3 * c03.y);
            T0[b] = make_float2(s0 + p1.x + p2.x + p3.x, p1.y + p2.y + p3.y);
            T1[b] = make_float2(s0 - p1.x + p2.x - p3.x, -p1.y + p2.y - p3.y);
        }
    } else {
        const F2* r1 = xp1[rr];
#pragma unroll
        for (int b = 0; b < 8; ++b) {
            int x0 = c + 4 * b;
            F2 a0 = r1[x0],      b0 = r1[x0 + 128];
            F2 a1 = r1[x0 + 32], b1 = r1[x0 + 160];
            F2 a2 = r1[x0 + 64], b2 = r1[x0 + 192];
            F2 a3 = r1[x0 + 96], b3 = r1[x0 + 224];
            F2 s0 = make_float2(fmaf(sgn, b0.x, a0.x), fmaf(sgn, b0.y, a0.y));
            F2 s1 = make_float2(fmaf(sgn, b1.x, a1.x), fmaf(sgn, b1.y, a1.y));
            F2 s2 = make_float2(fmaf(sgn, b2.x, a2.x), fmaf(sgn, b2.y, a2.y));
            F2 s3 = make_float2(fmaf(sgn, b3.x, a3.x), fmaf(sgn, b3.y, a3.y));
            F2 p1 = cmul(s1, c01);
            F2 p2 = cmul(s2, c02);
            F2 p3 = cmul(s3, c03);
            T0[b] = make_float2(s0.x + p1.x + p2.x + p3.x, s0.y + p1.y + p2.y + p3.y);
            T1[b] = make_float2(s0.x - p1.x + p2.x - p3.x, s0.y - p1.y + p2.y - p3.y);
        }
    }

    // ACC: acc[u] = tw4c[u] * sum_b TW16[(u*b)&15] * (tbase[b] * T_{u&1}[b])
    F2 acc0 = make_float2(0.f, 0.f), acc1 = acc0, acc2 = acc0, acc3 = acc0;
#pragma unroll
    for (int b = 0; b < 8; ++b) {
        F2 tb = tw[(kxg * (c + 4 * b)) & 255];
        F2 q0 = cmul(tb, T0[b]);
        F2 q1 = cmul(tb, T1[b]);
        acc0.x += q0.x; acc0.y += q0.y;
        {
            const float Cx = TW16X[(2 * b) & 15], Cy = TW16Y[(2 * b) & 15];
            acc2.x += q0.x * Cx - q0.y * Cy;
            acc2.y += q0.x * Cy + q0.y * Cx;
        }
        {
            const float Cx = TW16X[b & 15], Cy = TW16Y[b & 15];
            acc1.x += q1.x * Cx - q1.y * Cy;
            acc1.y += q1.x * Cy + q1.y * Cx;
        }
        {
            const float Cx = TW16X[(3 * b) & 15], Cy = TW16Y[(3 * b) & 15];
            acc3.x += q1.x * Cx - q1.y * Cy;
            acc3.y += q1.x * Cy + q1.y * Cx;
        }
    }
    acc1 = cmul(acc1, f1);
    acc2 = cmul(acc2, f2);
    acc3 = cmul(acc3, f3);

    {
        const int base = (((rr * 2 + kz) * 16 + kxg) << 2) + c;  // kx = kxg + 4u
        part[base]       = acc0;
        part[base + 16]  = acc1;
        part[base + 32]  = acc2;
        part[base + 48]  = acc3;
    }
    __syncthreads();
    {
        int rr2 = tid >> 5, kz2 = (tid >> 4) & 1, kx2 = tid & 15;
        const F2* p = &part[((rr2 * 2 + kz2) * 16 + kx2) << 2];
        F2 r = p[0];
        r.x += p[1].x + p[2].x + p[3].x;
        r.y += p[1].y + p[2].y + p[3].y;
        y[((size_t)(blk * 8 + rr2) * 2 + kz2) * 16 + kx2] = r;
    }
}

// ---------------------------------------------------------------------------
// K2a: y [(b,i),t,kz,kx] -> x_ft [b][s(32)][kz][kx][i] complex
// x_ft[s] = sum_t y[t] e^{-2pi i kt(s) t/128}, kt = s (s<16) else 96+s
// ---------------------------------------------------------------------------
__global__ __launch_bounds__(256) void k2a_fwd_t(const F2* __restrict__ y,
                                                 F2* __restrict__ xft) {
    __shared__ F2 yL[128][16];
    const int tid = threadIdx.x;
    const int bi = blockIdx.x >> 1, kz = blockIdx.x & 1;   // 512 blocks
#pragma unroll
    for (int j = 0; j < 8; ++j) {
        int item = tid + 256 * j;       // 2048 = 128 t * 16 kx
        int t = item >> 4, kx = item & 15;
        yL[t][kx] = y[((size_t)(bi * 128 + t) * 2 + kz) * 16 + kx];
    }
    __syncthreads();

    const int kx = tid & 15, sg = tid >> 4;   // sg in [0,16)
    F2 rotA = make_float2(1.f, 0.f), rotB = make_float2(1.f, 0.f), stepA, stepB;
    sincosf(-TWO_PI * (float)sg * (1.0f / 128.0f), &stepA.y, &stepA.x);
    sincosf(-TWO_PI * (float)(112 + sg) * (1.0f / 128.0f), &stepB.y, &stepB.x);
    F2 accA = make_float2(0.f, 0.f), accB = make_float2(0.f, 0.f);
#pragma unroll 8
    for (int t = 0; t < 128; ++t) {
        F2 v = yL[t][kx];
        accA = cmac(accA, v, rotA);
        accB = cmac(accB, v, rotB);
        rotA = cmul(rotA, stepA);
        rotB = cmul(rotB, stepB);
    }
    const int b = bi >> 5, i = bi & 31;
    xft[(((size_t)(b * 32 + sg) * 2 + kz) * 16 + kx) * 32 + i] = accA;
    xft[(((size_t)(b * 32 + (16 + sg)) * 2 + kz) * 16 + kx) * 32 + i] = accB;
}

// ---------------------------------------------------------------------------
// K2b: mode mix. block per (s,kx) (512 blocks); thread = (b,o).
// ---------------------------------------------------------------------------
__global__ __launch_bounds__(256) void k2b_mix(const F2* __restrict__ xft,
                                               const float* __restrict__ w1re,
                                               const float* __restrict__ w1im,
                                               const float* __restrict__ w2re,
                                               const float* __restrict__ w2im,
                                               F2* __restrict__ blkout) {
    __shared__ F2 xL[512];            // [b][kz][i]
    __shared__ F2 wcL[2][32][32];     // [kz][i][o] (re, im)
    const int tid = threadIdx.x;
    const int s = blockIdx.x >> 4, kx = blockIdx.x & 15;
#pragma unroll
    for (int j = 0; j < 2; ++j) {
        int item = tid + 256 * j;     // 512 = 8b * 2kz * 32i
        int b = item >> 6, kz = (item >> 5) & 1, i = item & 31;
        xL[item] = xft[(((size_t)(b * 32 + s) * 2 + kz) * 16 + kx) * 32 + i];
    }
    const float* bre = (s < 16) ? w1re : w2re;
    const float* bim = (s < 16) ? w1im : w2im;
    const int m1 = s & 15;
#pragma unroll
    for (int j = 0; j < 4; ++j) {
        int iop = tid + 256 * j;      // 1024 = 32i * 32o
        int i = iop >> 5, o = iop & 31;
        size_t g = (((size_t)(i * 32 + o) * 16 + m1) * 16 + kx) * 3;  // m3=0,1 adjacent
        wcL[0][i][o] = make_float2(bre[g], bim[g]);
        wcL[1][i][o] = make_float2(bre[g + 1], bim[g + 1]);
    }
    __syncthreads();

    const int b = tid >> 5, o = tid & 31;
#pragma unroll
    for (int kz = 0; kz < 2; ++kz) {
        F2 acc = make_float2(0.f, 0.f);
#pragma unroll 8
        for (int i = 0; i < 32; ++i) {
            F2 xv = xL[(b * 2 + kz) * 32 + i];   // broadcast across o
            F2 wv = wcL[kz][i][o];
            acc.x += xv.x * wv.x - xv.y * wv.y;
            acc.y += xv.x * wv.y + xv.y * wv.x;
        }
        blkout[(((size_t)(b * 32 + o) * 32 + s) * 2 + kz) * 16 + kx] = acc;
    }
}

// ---------------------------------------------------------------------------
// K23 v3: fused inverse-t + inverse-x + irfft(P=3).
// block = (bo, tc) (1024 blocks). Phase 1 = K2c body -> hT[32][32] in LDS.
// Phase 2 = K3 body reading hT, staged in oL, coalesced float4 write-back.
// History: v1 (plain bounds) -> 244 VGPR, 2 blk/CU, 83 us.
//          v2 (bounds(256,4)) -> compiler drove VGPR to 64, SPILLED phase-1
//          state (FETCH 4.3->86 MB, WRITE +165 MB), 103 us.
// v3: bounds(256,3) -> cap ~170 VGPR: forbids the 244 blowup, leaves room
//     for the ~100 live regs so no spills. unroll 1 + LDS pool kept.
// ---------------------------------------------------------------------------
__global__ __launch_bounds__(256, 3) void k23_inv_tx(const F2* __restrict__ blkin,
                                                     float* __restrict__ out) {
    // pool: phase 1 = bL[1024] F2 (8 KB); phase 2 = oL[8][768] float (24 KB)
    __shared__ __align__(16) unsigned char pool[24576];
    __shared__ F2 hT[32][32];                            // [t_local][col]
    F2* bL = (F2*)pool;
    float (*oL)[768] = (float (*)[768])pool;
    const int tid = threadIdx.x;
    const int bo = blockIdx.x >> 2, tc = blockIdx.x & 3; // 1024 blocks

#pragma unroll
    for (int j = 0; j < 4; ++j) {
        int item = tid + 256 * j;
        bL[item] = blkin[(size_t)bo * 1024 + item];
    }
    __syncthreads();

    // ---- phase 1: inverse t (verbatim K2c compute) ----
    {
        const int col = tid & 31, tl = tid >> 5;  // t = 32*tc + tl + 8*q
        F2 accA[4], accB[4], w[4], stp[4];
#pragma unroll
        for (int q = 0; q < 4; ++q) {
            accA[q] = make_float2(0.f, 0.f);
            accB[q] = make_float2(0.f, 0.f);
            w[q] = make_float2(1.f, 0.f);
            int t = 32 * tc + tl + 8 * q;
            sincosf(TWO_PI * (float)t * (1.0f / 128.0f), &stp[q].y, &stp[q].x);
        }
#pragma unroll 4
        for (int sp = 0; sp < 16; ++sp) {
            F2 bA = bL[sp * 32 + col];
            F2 bB = bL[(16 + sp) * 32 + col];
#pragma unroll
            for (int q = 0; q < 4; ++q) {
                accA[q] = cmac(accA[q], bA, w[q]);
                accB[q] = cmac(accB[q], bB, w[q]);
                w[q] = cmul(w[q], stp[q]);
            }
        }
        F2 phase;
        sincosf(-TWO_PI * (float)tl * (1.0f / 8.0f), &phase.y, &phase.x);
#pragma unroll
        for (int q = 0; q < 4; ++q) {
            hT[tl + 8 * q][col] = cmac(accA[q], phase, accB[q]);
        }
    }
    __syncthreads();   // hT ready; bL dead -> pool becomes oL

    // ---- phase 2: inverse x + irfft(P=3), 4 rounds of 8 t-rows ----
    const int xg = tid & 31, tl2 = tid >> 5;  // tl2 in [0,8)
    const float n = 1.0f / 98304.0f;          // 1/(128*256*3)
    for (int rd = 0; rd < 4; ++rd) {
        const F2* hrow = &hT[rd * 8 + tl2][0];
        float* o = oL[tl2];
#pragma unroll 1
        for (int j = 0; j < 4; ++j) {
            const int x = xg + 32 * j;        // x in [0,128)
            F2 w = make_float2(1.f, 0.f), r;
            sincosf(TWO_PI * (float)x * (1.0f / 256.0f), &r.y, &r.x);
            float e0 = 0.f, o0 = 0.f;
            F2 e1 = make_float2(0.f, 0.f), o1 = make_float2(0.f, 0.f);
#pragma unroll
            for (int k2 = 0; k2 < 8; ++k2) {
                {   // even kx = 2*k2
                    F2 h0 = hrow[2 * k2], h1 = hrow[16 + 2 * k2];
                    e0 += h0.x * w.x - h0.y * w.y;
                    e1.x += h1.x * w.x - h1.y * w.y;
                    e1.y += h1.x * w.y + h1.y * w.x;
                    w = cmul(w, r);
                }
                {   // odd kx = 2*k2+1
                    F2 h0 = hrow[2 * k2 + 1], h1 = hrow[16 + 2 * k2 + 1];
                    o0 += h0.x * w.x - h0.y * w.y;
                    o1.x += h1.x * w.x - h1.y * w.y;
                    o1.y += h1.x * w.y + h1.y * w.x;
                    w = cmul(w, r);
                }
            }
            {
                float g0 = e0 + o0, g1r = e1.x + o1.x, g1i = e1.y + o1.y;
                o[x * 3 + 0] = n * (g0 + 2.f * g1r);
                o[x * 3 + 1] = n * (g0 - g1r - SQRT3 * g1i);
                o[x * 3 + 2] = n * (g0 - g1r + SQRT3 * g1i);
            }
            {
                float g0 = e0 - o0, g1r = e1.x - o1.x, g1i = e1.y - o1.y;
                int xb = x + 128;
                o[xb * 3 + 0] = n * (g0 + 2.f * g1r);
                o[xb * 3 + 1] = n * (g0 - g1r - SQRT3 * g1i);
                o[xb * 3 + 2] = n * (g0 - g1r + SQRT3 * g1i);
            }
        }
        __syncthreads();
        {   // coalesced write-back of 8 rows: 1536 float4
            float4* dst = (float4*)(out + ((size_t)bo * 128 + 32 * tc + 8 * rd) * 768);
            const float4* src = (const float4*)pool;
#pragma unroll
            for (int k = 0; k < 6; ++k) dst[tid + 256 * k] = src[tid + 256 * k];
        }
        __syncthreads();   // before oL is overwritten next round
    }
}

// ---------------------------------------------------------------------------
extern "C" void kernel_launch(void* const* d_in, const int* in_sizes, int n_in,
                              void* d_out, int out_size, void* d_ws, size_t ws_size,
                              hipStream_t stream) {
    const float* x    = (const float*)d_in[0];
    const float* w1re = (const float*)d_in[1];
    const float* w1im = (const float*)d_in[2];
    const float* w2re = (const float*)d_in[3];
    const float* w2im = (const float*)d_in[4];
    float* out = (float*)d_out;

    // workspace layout (float2 units): y 1048576 | xft 262144 | blk 262144
    F2* y   = (F2*)d_ws;
    F2* xft = y + 1048576;
    F2* bk  = xft + 262144;

    hipLaunchKernelGGL(k1_fwd_x,   dim3(4096), dim3(256), 0, stream, x, y);
    hipLaunchKernelGGL(k2a_fwd_t,  dim3(512),  dim3(256), 0, stream, y, xft);
    hipLaunchKernelGGL(k2b_mix,    dim3(512),  dim3(256), 0, stream, xft,
                       w1re, w1im, w2re, w2im, bk);
    hipLaunchKernelGGL(k23_inv_tx, dim3(1024), dim3(256), 0, stream, bk, out);
}

// Round 7
// 252.490 us; speedup vs baseline: 1.2089x; 1.0153x over previous
//
#include <hip/hip_runtime.h>
#include <math.h>

// GNO2d spectral conv, factored into pruned DFT stages (fp32 throughout).
// B=8, Ci=Co=32, T=128, X=256, P=3; modes: kt in {0..15}u{112..127}, kx 0..15, kz 0..1.
// Structure: five kernels (fusion of K2c+K3 tried r4-r6: structurally worse, closed).
typedef float2 F2;

__device__ __forceinline__ F2 cmul(F2 a, F2 b) {
    return make_float2(a.x * b.x - a.y * b.y, a.x * b.y + a.y * b.x);
}
__device__ __forceinline__ F2 cmac(F2 acc, F2 a, F2 b) {
    acc.x += a.x * b.x - a.y * b.y;
    acc.y += a.x * b.y + a.y * b.x;
    return acc;
}
// z * (-i)^k  (quarter-turn rotations: component swaps/negates, free)
__device__ __forceinline__ F2 mulmi(F2 z, int k) {
    switch (k & 3) {
        case 0: return z;
        case 1: return make_float2(z.y, -z.x);
        case 2: return make_float2(-z.x, -z.y);
        default: return make_float2(-z.y, z.x);
    }
}

#define TWO_PI 6.283185307179586f
#define SQRT3_2 0.8660254037844386f
#define SQRT3 1.7320508075688772f

// TW16[k] = e^{-2pi i k/16} as constexpr tables -> constant-folded after unroll.
__device__ constexpr float TW16X[16] = {
    1.f,  0.923879533f,  0.707106781f,  0.382683432f,  0.f, -0.382683432f,
    -0.707106781f, -0.923879533f, -1.f, -0.923879533f, -0.707106781f,
    -0.382683432f, 0.f,  0.382683432f,  0.707106781f,  0.923879533f};
__device__ constexpr float TW16Y[16] = {
    0.f, -0.382683432f, -0.707106781f, -0.923879533f, -1.f, -0.923879533f,
    -0.707106781f, -0.382683432f, 0.f,  0.382683432f,  0.707106781f,
    0.923879533f,  1.f,  0.923879533f,  0.707106781f,  0.382683432f};

// ---------------------------------------------------------------------------
// K1 v5: x [row=(b,i,t)][256][3] -> y [row][kz(2)][kx(16)] complex
// Factored twiddle: tw[kx*x] = tw[4uc]*TW16[(ub)&15]*tbase[b]*c0(a)*(-1)^(au).
// LDS stride 260 (== 4 mod 32): hot-loop reads conflict-free.
// ---------------------------------------------------------------------------
__global__ __launch_bounds__(256) void k1_fwd_x(const float* __restrict__ x,
                                                F2* __restrict__ y) {
    __shared__ float xp0[8][260];
    __shared__ F2    xp1[8][260];
    __shared__ F2    tw[256];       // tw[n] = e^{-2pi i n/256}
    __shared__ F2    part[1024];    // [rr][kz][kx][c]
    const int tid = threadIdx.x;
    const int blk = blockIdx.x;     // 8 rows per block, 4096 blocks

    {   // twiddle table
        float sv, cv;
        sincosf(-TWO_PI * (float)tid * (1.0f / 256.0f), &sv, &cv);
        tw[tid] = make_float2(cv, sv);
    }
    // p-stage into LDS
#pragma unroll
    for (int j = 0; j < 8; ++j) {
        int item = tid + 256 * j;           // 2048 = 8 rows * 256 x
        int row = item >> 8, xx = item & 255;
        const float* src = x + ((size_t)(blk * 8 + row) * 256 + xx) * 3;
        float a = src[0], b = src[1], c = src[2];
        xp0[row][xx] = a + b + c;
        xp1[row][xx] = make_float2(a - 0.5f * (b + c), SQRT3_2 * (c - b));
    }
    __syncthreads();

    const int kz = tid >> 7, rr = (tid >> 4) & 7, kxg = (tid >> 2) & 3, c = tid & 3;
    const float sgn = (kxg & 1) ? -1.0f : 1.0f;

    // c0(a) = tw[(32 a kxg) & 255], a = 1..3
    const F2 c01 = tw[(32 * kxg) & 255];
    const F2 c02 = tw[(64 * kxg) & 255];
    const F2 c03 = tw[(96 * kxg) & 255];
    // tw4c[u] = tw[(4 u c) & 255], u = 1..3
    const F2 f1 = tw[(4 * c) & 255];
    const F2 f2 = tw[(8 * c) & 255];
    const F2 f3 = tw[(12 * c) & 255];

    F2 T0[8], T1[8];
    if (kz == 0) {
        const float* r0 = xp0[rr];
#pragma unroll
        for (int b = 0; b < 8; ++b) {
            int x0 = c + 4 * b;
            float s0 = fmaf(sgn, r0[x0 + 128], r0[x0]);
            float s1 = fmaf(sgn, r0[x0 + 160], r0[x0 + 32]);
            float s2 = fmaf(sgn, r0[x0 + 192], r0[x0 + 64]);
            float s3 = fmaf(sgn, r0[x0 + 224], r0[x0 + 96]);
            F2 p1 = make_float2(s1 * c01.x, s1 * c01.y);
            F2 p2 = make_float2(s2 * c02.x, s2 * c02.y);
            F2 p3 = make_float2(s3 * c03.x, s3 * c03.y);
            T0[b] = make_float2(s0 + p1.x + p2.x + p3.x, p1.y + p2.y + p3.y);
            T1[b] = make_float2(s0 - p1.x + p2.x - p3.x, -p1.y + p2.y - p3.y);
        }
    } else {
        const F2* r1 = xp1[rr];
#pragma unroll
        for (int b = 0; b < 8; ++b) {
            int x0 = c + 4 * b;
            F2 a0 = r1[x0],      b0 = r1[x0 + 128];
            F2 a1 = r1[x0 + 32], b1 = r1[x0 + 160];
            F2 a2 = r1[x0 + 64], b2 = r1[x0 + 192];
            F2 a3 = r1[x0 + 96], b3 = r1[x0 + 224];
            F2 s0 = make_float2(fmaf(sgn, b0.x, a0.x), fmaf(sgn, b0.y, a0.y));
            F2 s1 = make_float2(fmaf(sgn, b1.x, a1.x), fmaf(sgn, b1.y, a1.y));
            F2 s2 = make_float2(fmaf(sgn, b2.x, a2.x), fmaf(sgn, b2.y, a2.y));
            F2 s3 = make_float2(fmaf(sgn, b3.x, a3.x), fmaf(sgn, b3.y, a3.y));
            F2 p1 = cmul(s1, c01);
            F2 p2 = cmul(s2, c02);
            F2 p3 = cmul(s3, c03);
            T0[b] = make_float2(s0.x + p1.x + p2.x + p3.x, s0.y + p1.y + p2.y + p3.y);
            T1[b] = make_float2(s0.x - p1.x + p2.x - p3.x, s0.y - p1.y + p2.y - p3.y);
        }
    }

    // ACC: acc[u] = tw4c[u] * sum_b TW16[(u*b)&15] * (tbase[b] * T_{u&1}[b])
    F2 acc0 = make_float2(0.f, 0.f), acc1 = acc0, acc2 = acc0, acc3 = acc0;
#pragma unroll
    for (int b = 0; b < 8; ++b) {
        F2 tb = tw[(kxg * (c + 4 * b)) & 255];
        F2 q0 = cmul(tb, T0[b]);
        F2 q1 = cmul(tb, T1[b]);
        acc0.x += q0.x; acc0.y += q0.y;
        {
            const float Cx = TW16X[(2 * b) & 15], Cy = TW16Y[(2 * b) & 15];
            acc2.x += q0.x * Cx - q0.y * Cy;
            acc2.y += q0.x * Cy + q0.y * Cx;
        }
        {
            const float Cx = TW16X[b & 15], Cy = TW16Y[b & 15];
            acc1.x += q1.x * Cx - q1.y * Cy;
            acc1.y += q1.x * Cy + q1.y * Cx;
        }
        {
            const float Cx = TW16X[(3 * b) & 15], Cy = TW16Y[(3 * b) & 15];
            acc3.x += q1.x * Cx - q1.y * Cy;
            acc3.y += q1.x * Cy + q1.y * Cx;
        }
    }
    acc1 = cmul(acc1, f1);
    acc2 = cmul(acc2, f2);
    acc3 = cmul(acc3, f3);

    {
        const int base = (((rr * 2 + kz) * 16 + kxg) << 2) + c;  // kx = kxg + 4u
        part[base]       = acc0;
        part[base + 16]  = acc1;
        part[base + 32]  = acc2;
        part[base + 48]  = acc3;
    }
    __syncthreads();
    {
        int rr2 = tid >> 5, kz2 = (tid >> 4) & 1, kx2 = tid & 15;
        const F2* p = &part[((rr2 * 2 + kz2) * 16 + kx2) << 2];
        F2 r = p[0];
        r.x += p[1].x + p[2].x + p[3].x;
        r.y += p[1].y + p[2].y + p[3].y;
        y[((size_t)(blk * 8 + rr2) * 2 + kz2) * 16 + kx2] = r;
    }
}

// ---------------------------------------------------------------------------
// K2a v2: y [(b,i),t,kz,kx] -> x_ft [b][s(32)][kz][kx][i] complex
// x_ft[s] = sum_t y[t] e^{-2pi i kt(s) t/128}, kt = s (s<16) else 96+s.
// v2: t split into 4 chunks of 32 with 4 INDEPENDENT rotator chains
// (critical path 128 -> 32 cmuls; this kernel runs at 2 blocks/CU so the
// serial chain was latency-exposed). Chunk phase offsets are exactly
// (-i)^(sg*q) for BOTH kt=sg and kt=112+sg (112*32*q/128 = 28q full turns),
// applied as free quarter-turn swaps at the end.
// ---------------------------------------------------------------------------
__global__ __launch_bounds__(256) void k2a_fwd_t(const F2* __restrict__ y,
                                                 F2* __restrict__ xft) {
    __shared__ F2 yL[128][16];
    const int tid = threadIdx.x;
    const int bi = blockIdx.x >> 1, kz = blockIdx.x & 1;   // 512 blocks
#pragma unroll
    for (int j = 0; j < 8; ++j) {
        int item = tid + 256 * j;       // 2048 = 128 t * 16 kx
        int t = item >> 4, kx = item & 15;
        yL[t][kx] = y[((size_t)(bi * 128 + t) * 2 + kz) * 16 + kx];
    }
    __syncthreads();

    const int kx = tid & 15, sg = tid >> 4;   // sg in [0,16)
    F2 stepA, stepB;
    sincosf(-TWO_PI * (float)sg * (1.0f / 128.0f), &stepA.y, &stepA.x);
    sincosf(-TWO_PI * (float)(112 + sg) * (1.0f / 128.0f), &stepB.y, &stepB.x);
    F2 accA[4], accB[4], rotA[4], rotB[4];
#pragma unroll
    for (int q = 0; q < 4; ++q) {
        accA[q] = make_float2(0.f, 0.f);
        accB[q] = make_float2(0.f, 0.f);
        rotA[q] = make_float2(1.f, 0.f);
        rotB[q] = make_float2(1.f, 0.f);
    }
#pragma unroll 4
    for (int tt = 0; tt < 32; ++tt) {
#pragma unroll
        for (int q = 0; q < 4; ++q) {
            F2 v = yL[32 * q + tt][kx];
            accA[q] = cmac(accA[q], v, rotA[q]);
            accB[q] = cmac(accB[q], v, rotB[q]);
            rotA[q] = cmul(rotA[q], stepA);
            rotB[q] = cmul(rotB[q], stepB);
        }
    }
    // combine: chunk q carries phase (-i)^(sg*q)
    F2 accAt = accA[0], accBt = accB[0];
#pragma unroll
    for (int q = 1; q < 4; ++q) {
        F2 ca = mulmi(accA[q], sg * q);
        F2 cb = mulmi(accB[q], sg * q);
        accAt.x += ca.x; accAt.y += ca.y;
        accBt.x += cb.x; accBt.y += cb.y;
    }
    const int b = bi >> 5, i = bi & 31;
    xft[(((size_t)(b * 32 + sg) * 2 + kz) * 16 + kx) * 32 + i] = accAt;
    xft[(((size_t)(b * 32 + (16 + sg)) * 2 + kz) * 16 + kx) * 32 + i] = accBt;
}

// ---------------------------------------------------------------------------
// K2b: mode mix. block per (s,kx) (512 blocks); thread = (b,o).
// ---------------------------------------------------------------------------
__global__ __launch_bounds__(256) void k2b_mix(const F2* __restrict__ xft,
                                               const float* __restrict__ w1re,
                                               const float* __restrict__ w1im,
                                               const float* __restrict__ w2re,
                                               const float* __restrict__ w2im,
                                               F2* __restrict__ blkout) {
    __shared__ F2 xL[512];            // [b][kz][i]
    __shared__ F2 wcL[2][32][32];     // [kz][i][o] (re, im)
    const int tid = threadIdx.x;
    const int s = blockIdx.x >> 4, kx = blockIdx.x & 15;
#pragma unroll
    for (int j = 0; j < 2; ++j) {
        int item = tid + 256 * j;     // 512 = 8b * 2kz * 32i
        int b = item >> 6, kz = (item >> 5) & 1, i = item & 31;
        xL[item] = xft[(((size_t)(b * 32 + s) * 2 + kz) * 16 + kx) * 32 + i];
    }
    const float* bre = (s < 16) ? w1re : w2re;
    const float* bim = (s < 16) ? w1im : w2im;
    const int m1 = s & 15;
#pragma unroll
    for (int j = 0; j < 4; ++j) {
        int iop = tid + 256 * j;      // 1024 = 32i * 32o
        int i = iop >> 5, o = iop & 31;
        size_t g = (((size_t)(i * 32 + o) * 16 + m1) * 16 + kx) * 3;  // m3=0,1 adjacent
        wcL[0][i][o] = make_float2(bre[g], bim[g]);
        wcL[1][i][o] = make_float2(bre[g + 1], bim[g + 1]);
    }
    __syncthreads();

    const int b = tid >> 5, o = tid & 31;
#pragma unroll
    for (int kz = 0; kz < 2; ++kz) {
        F2 acc = make_float2(0.f, 0.f);
#pragma unroll 8
        for (int i = 0; i < 32; ++i) {
            F2 xv = xL[(b * 2 + kz) * 32 + i];   // broadcast across o
            F2 wv = wcL[kz][i][o];
            acc.x += xv.x * wv.x - xv.y * wv.y;
            acc.y += xv.x * wv.y + xv.y * wv.x;
        }
        blkout[(((size_t)(b * 32 + o) * 32 + s) * 2 + kz) * 16 + kx] = acc;
    }
}

// ---------------------------------------------------------------------------
// K2c: inverse t. block per (bo, tchunk) (1024 blocks); thread = (tl, col),
// each thread owns 4 t-values => 32 floats of state, no spills.
// ---------------------------------------------------------------------------
__global__ __launch_bounds__(256) void k2c_inv_t(const F2* __restrict__ blkin,
                                                 F2* __restrict__ h) {
    __shared__ F2 bL[1024];   // [s][col], col = kz*16+kx
    const int tid = threadIdx.x;
    const int bo = blockIdx.x >> 2, tc = blockIdx.x & 3;   // 1024 blocks
#pragma unroll
    for (int j = 0; j < 4; ++j) {
        int item = tid + 256 * j;
        bL[item] = blkin[(size_t)bo * 1024 + item];
    }
    __syncthreads();

    const int col = tid & 31, tl = tid >> 5;  // t = 32*tc + tl + 8*q
    F2 accA[4], accB[4], w[4], stp[4];
#pragma unroll
    for (int q = 0; q < 4; ++q) {
        accA[q] = make_float2(0.f, 0.f);
        accB[q] = make_float2(0.f, 0.f);
        w[q] = make_float2(1.f, 0.f);
        int t = 32 * tc + tl + 8 * q;
        sincosf(TWO_PI * (float)t * (1.0f / 128.0f), &stp[q].y, &stp[q].x);
    }
#pragma unroll 4
    for (int sp = 0; sp < 16; ++sp) {
        F2 bA = bL[sp * 32 + col];
        F2 bB = bL[(16 + sp) * 32 + col];
#pragma unroll
        for (int q = 0; q < 4; ++q) {
            accA[q] = cmac(accA[q], bA, w[q]);
            accB[q] = cmac(accB[q], bB, w[q]);
            w[q] = cmul(w[q], stp[q]);
        }
    }
    F2 phase;
    sincosf(-TWO_PI * (float)tl * (1.0f / 8.0f), &phase.y, &phase.x);
#pragma unroll
    for (int q = 0; q < 4; ++q) {
        int t = 32 * tc + tl + 8 * q;
        F2 r = cmac(accA[q], phase, accB[q]);   // accA + phase*accB
        h[((size_t)bo * 128 + t) * 32 + col] = r;
    }
}

// ---------------------------------------------------------------------------
// K3 v3: inverse x + irfft(P=3). block = 2 rows, thread = x in [0,128).
// LDS-staged output, coalesced float4 write-back.
// v3: independent even/odd rotator chains (we step r^2, wo = r*we) instead
// of one shared 16-long chain -> critical path halved, 2x ILP.
// ---------------------------------------------------------------------------
__global__ __launch_bounds__(256) void k3_inv_x(const F2* __restrict__ h,
                                                float* __restrict__ out) {
    __shared__ F2 hL[64];      // [2 rows][32 cols]
    __shared__ __align__(16) float oL[1536]; // [2 rows][768] staged output
    const int tid = threadIdx.x;
    const int blk = blockIdx.x;   // 16384 blocks
    if (tid < 64) hL[tid] = h[(size_t)blk * 64 + tid];
    __syncthreads();

    const int rr = tid >> 7, x = tid & 127;   // row uniform per wave
    const F2* hrow = &hL[rr * 32];
    F2 r;
    sincosf(TWO_PI * (float)x * (1.0f / 256.0f), &r.y, &r.x);
    const F2 r2 = cmul(r, r);
    F2 we = make_float2(1.f, 0.f), wo = r;
    float e0 = 0.f, o0 = 0.f;
    F2 e1 = make_float2(0.f, 0.f), o1 = make_float2(0.f, 0.f);
#pragma unroll
    for (int k2 = 0; k2 < 8; ++k2) {
        {   // even kx = 2*k2 (twiddle we = r^(2k2))
            F2 h0 = hrow[2 * k2], h1 = hrow[16 + 2 * k2];
            e0 += h0.x * we.x - h0.y * we.y;
            e1.x += h1.x * we.x - h1.y * we.y;
            e1.y += h1.x * we.y + h1.y * we.x;
        }
        {   // odd kx = 2*k2+1 (twiddle wo = r^(2k2+1))
            F2 h0 = hrow[2 * k2 + 1], h1 = hrow[16 + 2 * k2 + 1];
            o0 += h0.x * wo.x - h0.y * wo.y;
            o1.x += h1.x * wo.x - h1.y * wo.y;
            o1.y += h1.x * wo.y + h1.y * wo.x;
        }
        we = cmul(we, r2);
        wo = cmul(wo, r2);
    }
    const float n = 1.0f / 98304.0f;   // 1/(128*256*3)
    float* o = &oL[rr * 768];
    {
        float g0 = e0 + o0, g1r = e1.x + o1.x, g1i = e1.y + o1.y;
        o[x * 3 + 0] = n * (g0 + 2.f * g1r);
        o[x * 3 + 1] = n * (g0 - g1r - SQRT3 * g1i);
        o[x * 3 + 2] = n * (g0 - g1r + SQRT3 * g1i);
    }
    {
        float g0 = e0 - o0, g1r = e1.x - o1.x, g1i = e1.y - o1.y;
        int xb = x + 128;
        o[xb * 3 + 0] = n * (g0 + 2.f * g1r);
        o[xb * 3 + 1] = n * (g0 - g1r - SQRT3 * g1i);
        o[xb * 3 + 2] = n * (g0 - g1r + SQRT3 * g1i);
    }
    __syncthreads();
    {   // coalesced write-back: 384 float4 = 1536 floats
        float4* dst = (float4*)(out + (size_t)blk * 1536);
        const float4* src = (const float4*)oL;
        dst[tid] = src[tid];
        if (tid < 128) dst[tid + 256] = src[tid + 256];
    }
}

// ---------------------------------------------------------------------------
extern "C" void kernel_launch(void* const* d_in, const int* in_sizes, int n_in,
                              void* d_out, int out_size, void* d_ws, size_t ws_size,
                              hipStream_t stream) {
    const float* x    = (const float*)d_in[0];
    const float* w1re = (const float*)d_in[1];
    const float* w1im = (const float*)d_in[2];
    const float* w2re = (const float*)d_in[3];
    const float* w2im = (const float*)d_in[4];
    float* out = (float*)d_out;

    // workspace layout (float2 units): y 1048576 | xft 262144 | blk 262144 | h 1048576
    F2* y   = (F2*)d_ws;
    F2* xft = y + 1048576;
    F2* bk  = xft + 262144;
    F2* h   = bk + 262144;

    hipLaunchKernelGGL(k1_fwd_x,  dim3(4096),  dim3(256), 0, stream, x, y);
    hipLaunchKernelGGL(k2a_fwd_t, dim3(512),   dim3(256), 0, stream, y, xft);
    hipLaunchKernelGGL(k2b_mix,   dim3(512),   dim3(256), 0, stream, xft,
                       w1re, w1im, w2re, w2im, bk);
    hipLaunchKernelGGL(k2c_inv_t, dim3(1024),  dim3(256), 0, stream, bk, h);
    hipLaunchKernelGGL(k3_inv_x,  dim3(16384), dim3(256), 0, stream, h, out);
}